// Round 1
// baseline (2680.716 us; speedup 1.0000x reference)
//
#include <hip/hip_runtime.h>
#include <hip/hip_bf16.h>

// Head: causal single-head attention forward.
// B=8, T=2048, C=1024, H=1024. Inputs fp32: x[B,T,C], Wk[H,C], Wq[H,C], Wv[H,C].
// Outputs (concat in d_out): out[B,T,H] fp32, wei[B,T,T] fp32.
//
// Numerics: logits std ~1024 -> softmax near-one-hot -> q/k path must be fp32
// precision (bf16 would flip argmaxes and blow the wei threshold ~0.02).
// v path is tolerant (out threshold ~3.36) -> v stored bf16 in ws.
//
// ws layout: q fp32 [16384,1024] | k fp32 [16384,1024] | v bf16 [16384,1024]
//   = 67.1MB + 67.1MB + 33.5MB = 167.8MB
//
// Round 1: correctness-first fp32 vector GEMMs (no MFMA). 64x64x16 tiles,
// 256 threads, 4x4 acc/thread, LDS [16][68] (272B row stride: float4-aligned,
// 2-way bank aliasing = free on gfx950).

#define BB 8
#define TT 2048
#define CC 1024
#define HH 1024
#define BT (BB * TT)

// ---------------- Kernel 1: projections q,k (fp32) and v (bf16) --------------
// O[m,n] = sum_c A[m,c] * W[n,c]   (NT GEMM, both K-contiguous)
__global__ __launch_bounds__(256) void proj_kernel(
    const float* __restrict__ x,
    const float* __restrict__ Wq,
    const float* __restrict__ Wk,
    const float* __restrict__ Wv,
    float* __restrict__ q, float* __restrict__ k,
    __hip_bfloat16* __restrict__ v)
{
    __shared__ float As[16][68];
    __shared__ float Bs[16][68];

    const int m0 = blockIdx.x * 64;     // row tile in [0, BT)
    const int n0 = blockIdx.y * 64;     // col tile in [0, H)
    const int z  = blockIdx.z;          // 0:q 1:k 2:v
    const float* W = (z == 0) ? Wq : (z == 1) ? Wk : Wv;

    const int tid = threadIdx.x;
    const int lr  = tid >> 2;           // 0..63 load row
    const int lc  = (tid & 3) << 2;     // 0,4,8,12 load col (k)
    const int ty  = tid >> 4;           // 0..15
    const int tx  = tid & 15;           // 0..15

    float acc[4][4] = {};

    for (int kc = 0; kc < CC; kc += 16) {
        float4 av = *(const float4*)&x[(size_t)(m0 + lr) * CC + kc + lc];
        float4 bv = *(const float4*)&W[(size_t)(n0 + lr) * CC + kc + lc];
        __syncthreads();
        As[lc + 0][lr] = av.x; As[lc + 1][lr] = av.y;
        As[lc + 2][lr] = av.z; As[lc + 3][lr] = av.w;
        Bs[lc + 0][lr] = bv.x; Bs[lc + 1][lr] = bv.y;
        Bs[lc + 2][lr] = bv.z; Bs[lc + 3][lr] = bv.w;
        __syncthreads();
#pragma unroll
        for (int kk = 0; kk < 16; ++kk) {
            float4 a = *(const float4*)&As[kk][ty * 4];
            float4 b = *(const float4*)&Bs[kk][tx * 4];
            float af[4] = {a.x, a.y, a.z, a.w};
            float bf[4] = {b.x, b.y, b.z, b.w};
#pragma unroll
            for (int i = 0; i < 4; ++i)
#pragma unroll
                for (int j = 0; j < 4; ++j)
                    acc[i][j] += af[i] * bf[j];
        }
    }

    if (z == 2) {
#pragma unroll
        for (int i = 0; i < 4; ++i) {
            size_t o = (size_t)(m0 + ty * 4 + i) * HH + n0 + tx * 4;
#pragma unroll
            for (int j = 0; j < 4; ++j)
                v[o + j] = __float2bfloat16(acc[i][j]);
        }
    } else {
        float* O = (z == 0) ? q : k;
#pragma unroll
        for (int i = 0; i < 4; ++i) {
            size_t o = (size_t)(m0 + ty * 4 + i) * HH + n0 + tx * 4;
            *(float4*)&O[o] = make_float4(acc[i][0], acc[i][1], acc[i][2], acc[i][3]);
        }
    }
}

// ---------------- Kernel 2: wei_raw = (q k^T) / 32, lower-tri tiles ----------
__global__ __launch_bounds__(256) void qk_kernel(
    const float* __restrict__ q, const float* __restrict__ k,
    float* __restrict__ wei)
{
    const int st = blockIdx.x;          // s tile
    const int tt = blockIdx.y;          // t tile
    if (st > tt) return;                // strictly-above-diagonal: softmax writes 0
    const int b = blockIdx.z;

    const float* qb = q + (size_t)b * TT * HH;
    const float* kb = k + (size_t)b * TT * HH;
    float* wb = wei + (size_t)b * TT * TT;

    const int m0 = tt * 64;             // t rows
    const int n0 = st * 64;             // s cols

    __shared__ float As[16][68];
    __shared__ float Bs[16][68];

    const int tid = threadIdx.x;
    const int lr  = tid >> 2;
    const int lc  = (tid & 3) << 2;
    const int ty  = tid >> 4;
    const int tx  = tid & 15;

    float acc[4][4] = {};

    for (int kc = 0; kc < HH; kc += 16) {
        float4 av = *(const float4*)&qb[(size_t)(m0 + lr) * HH + kc + lc];
        float4 bv = *(const float4*)&kb[(size_t)(n0 + lr) * HH + kc + lc];
        __syncthreads();
        As[lc + 0][lr] = av.x; As[lc + 1][lr] = av.y;
        As[lc + 2][lr] = av.z; As[lc + 3][lr] = av.w;
        Bs[lc + 0][lr] = bv.x; Bs[lc + 1][lr] = bv.y;
        Bs[lc + 2][lr] = bv.z; Bs[lc + 3][lr] = bv.w;
        __syncthreads();
#pragma unroll
        for (int kk = 0; kk < 16; ++kk) {
            float4 a = *(const float4*)&As[kk][ty * 4];
            float4 b = *(const float4*)&Bs[kk][tx * 4];
            float af[4] = {a.x, a.y, a.z, a.w};
            float bf[4] = {b.x, b.y, b.z, b.w};
#pragma unroll
            for (int i = 0; i < 4; ++i)
#pragma unroll
                for (int j = 0; j < 4; ++j)
                    acc[i][j] += af[i] * bf[j];
        }
    }

    const float scale = 0.03125f;       // 1024^-0.5
#pragma unroll
    for (int i = 0; i < 4; ++i) {
        size_t o = (size_t)(m0 + ty * 4 + i) * TT + n0 + tx * 4;
        *(float4*)&wb[o] = make_float4(acc[i][0] * scale, acc[i][1] * scale,
                                       acc[i][2] * scale, acc[i][3] * scale);
    }
}

// ---------------- Kernel 3: causal row softmax in-place ----------------------
__global__ __launch_bounds__(256) void softmax_kernel(float* __restrict__ wei)
{
    const int t = blockIdx.x;
    const int b = blockIdx.y;
    float* row = wei + (size_t)b * TT * TT + (size_t)t * TT;
    const int n = t + 1;                // valid length
    const int tid = threadIdx.x;

    float vals[8];
    float mx = -INFINITY;
#pragma unroll
    for (int i = 0; i < 8; ++i) {
        int s = tid + i * 256;
        vals[i] = (s < n) ? row[s] : -INFINITY;
        mx = fmaxf(mx, vals[i]);
    }
#pragma unroll
    for (int off = 32; off > 0; off >>= 1)
        mx = fmaxf(mx, __shfl_down(mx, off));

    __shared__ float redm[4];
    __shared__ float reds[4];
    if ((tid & 63) == 0) redm[tid >> 6] = mx;
    __syncthreads();
    const float m = fmaxf(fmaxf(redm[0], redm[1]), fmaxf(redm[2], redm[3]));

    float sum = 0.f;
#pragma unroll
    for (int i = 0; i < 8; ++i) {
        vals[i] = __expf(vals[i] - m);  // exp(-inf)=0 for masked/pad lanes
        sum += vals[i];
    }
#pragma unroll
    for (int off = 32; off > 0; off >>= 1)
        sum += __shfl_down(sum, off);
    if ((tid & 63) == 0) reds[tid >> 6] = sum;
    __syncthreads();
    const float inv = 1.0f / (reds[0] + reds[1] + reds[2] + reds[3]);

#pragma unroll
    for (int i = 0; i < 8; ++i) {
        int s = tid + i * 256;
        row[s] = vals[i] * inv;         // masked entries: 0 * inv = 0 exactly
    }
}

// ---------------- Kernel 4: out = wei @ v (NN GEMM, K truncated causally) ----
__global__ __launch_bounds__(256) void out_kernel(
    const float* __restrict__ wei, const __hip_bfloat16* __restrict__ v,
    float* __restrict__ out)
{
    const int nt = blockIdx.x;          // h tile
    const int tt = blockIdx.y;          // t tile
    const int b  = blockIdx.z;

    const float* wb = wei + (size_t)b * TT * TT;
    const unsigned short* vb = (const unsigned short*)(v + (size_t)b * TT * HH);
    float* ob = out + (size_t)b * TT * HH;

    const int m0 = tt * 64;
    const int n0 = nt * 64;
    const int kend = (tt + 1) * 64;     // wei[t,s]=0 for s>t

    __shared__ float As[16][68];
    __shared__ float Bs[16][68];

    const int tid = threadIdx.x;
    const int lr  = tid >> 2;           // A: 0..63 t-row
    const int lc  = (tid & 3) << 2;     // A: k offset
    const int kr  = tid >> 4;           // B: 0..15 k-row
    const int h4  = (tid & 15) << 2;    // B: h offset
    const int ty  = tid >> 4;
    const int tx  = tid & 15;

    float acc[4][4] = {};

    for (int kc = 0; kc < kend; kc += 16) {
        float4 av = *(const float4*)&wb[(size_t)(m0 + lr) * TT + kc + lc];
        ushort4 bv = *(const ushort4*)&vb[(size_t)(kc + kr) * HH + n0 + h4];
        __syncthreads();
        As[lc + 0][lr] = av.x; As[lc + 1][lr] = av.y;
        As[lc + 2][lr] = av.z; As[lc + 3][lr] = av.w;
        Bs[kr][h4 + 0] = __uint_as_float((unsigned)bv.x << 16);
        Bs[kr][h4 + 1] = __uint_as_float((unsigned)bv.y << 16);
        Bs[kr][h4 + 2] = __uint_as_float((unsigned)bv.z << 16);
        Bs[kr][h4 + 3] = __uint_as_float((unsigned)bv.w << 16);
        __syncthreads();
#pragma unroll
        for (int kk = 0; kk < 16; ++kk) {
            float4 a = *(const float4*)&As[kk][ty * 4];
            float4 b2 = *(const float4*)&Bs[kk][tx * 4];
            float af[4] = {a.x, a.y, a.z, a.w};
            float bf[4] = {b2.x, b2.y, b2.z, b2.w};
#pragma unroll
            for (int i = 0; i < 4; ++i)
#pragma unroll
                for (int j = 0; j < 4; ++j)
                    acc[i][j] += af[i] * bf[j];
        }
    }

#pragma unroll
    for (int i = 0; i < 4; ++i) {
        size_t o = (size_t)(m0 + ty * 4 + i) * HH + n0 + tx * 4;
        *(float4*)&ob[o] = make_float4(acc[i][0], acc[i][1], acc[i][2], acc[i][3]);
    }
}

extern "C" void kernel_launch(void* const* d_in, const int* in_sizes, int n_in,
                              void* d_out, int out_size, void* d_ws, size_t ws_size,
                              hipStream_t stream)
{
    const float* x  = (const float*)d_in[0];   // [8,2048,1024]
    const float* Wk = (const float*)d_in[1];   // [1024,1024]
    const float* Wq = (const float*)d_in[2];
    const float* Wv = (const float*)d_in[3];

    float* out = (float*)d_out;                       // [8,2048,1024]
    float* wei = out + (size_t)BT * HH;               // [8,2048,2048]

    float* q = (float*)d_ws;                          // fp32 [16384,1024]
    float* k = q + (size_t)BT * HH;                   // fp32 [16384,1024]
    __hip_bfloat16* v = (__hip_bfloat16*)(k + (size_t)BT * HH);  // bf16 [16384,1024]

    proj_kernel<<<dim3(BT / 64, HH / 64, 3), 256, 0, stream>>>(x, Wq, Wk, Wv, q, k, v);
    qk_kernel<<<dim3(TT / 64, TT / 64, BB), 256, 0, stream>>>(q, k, wei);
    softmax_kernel<<<dim3(TT, BB), 256, 0, stream>>>(wei);
    out_kernel<<<dim3(HH / 64, TT / 64, BB), 256, 0, stream>>>(wei, v, out);
}

// Round 2
// 1150.815 us; speedup vs baseline: 2.3294x; 2.3294x over previous
//
#include <hip/hip_runtime.h>
#include <hip/hip_bf16.h>

// Head: causal single-head attention fwd. B=8,T=2048,C=H=1024, fp32 in.
// Outputs: out[B,T,H] fp32, wei[B,T,T] fp32 (concat in d_out).
//
// Round 2: split-f16 emulated-fp32 MFMA GEMMs.
//   x = hi + lo (f16 pair, residual ~2^-22 rel). GEMM = 3 MFMA passes
//   (hi*hi + hi*lo + lo*hi). Logit error ~2e-4 << 0.005 budget.
//   v path and wei@v are tolerant -> 1-pass f16.
// ws: qh,ql,kh,kl,v f16 [16384,1024] each = 5 x 32MB = 160MB (<= round-1 168MB).
//
// Tile structure: 128x128x32, 256 thr = 4 waves (2x2 of 64x64 wave-tiles),
// 4x4 16x16x32 mfma tiles/wave. LDS cells [khalf][row]*16B: frag
// ds_read_b128 is lane-consecutive -> conflict-free.
// Frag layouts (verified, learn_hip m89/m91): A/B[row=lane&15][k=(lane>>4)*8+j],
// C/D col=lane&15, row=(lane>>4)*4+reg.

#define BB 8
#define TT 2048
#define CC 1024
#define HH 1024
#define BT (BB * TT)

typedef _Float16 f16x8 __attribute__((ext_vector_type(8)));
typedef float f32x4 __attribute__((ext_vector_type(4)));

__device__ __forceinline__ void split8(const float* f, f16x8& hi, f16x8& lo) {
#pragma unroll
    for (int i = 0; i < 8; ++i) {
        _Float16 h = (_Float16)f[i];
        hi[i] = h;
        lo[i] = (_Float16)(f[i] - (float)h);
    }
}

// ---------------- Kernel 1: projections. q,k -> f16 hi/lo pairs; v -> f16 ----
// O[m,n] = sum_c X[m,c] * W[n,c]  (NT). 3-pass for q,k; 1-pass for v.
__global__ __launch_bounds__(256, 2) void proj_kernel(
    const float* __restrict__ x,
    const float* __restrict__ Wq, const float* __restrict__ Wk,
    const float* __restrict__ Wv,
    _Float16* __restrict__ qh, _Float16* __restrict__ ql,
    _Float16* __restrict__ kh, _Float16* __restrict__ kl,
    _Float16* __restrict__ vv)
{
    __shared__ _Float16 Ah[4096], Al[4096], Bh[4096], Bl[4096];

    const int n0 = blockIdx.x * 128;
    const int m0 = blockIdx.y * 128;
    const int z  = blockIdx.z;                  // 0:q 1:k 2:v
    const float* W = (z == 0) ? Wq : (z == 1) ? Wk : Wv;

    const int tid  = threadIdx.x;
    const int row  = tid & 127;
    const int khp  = tid >> 7;                  // 0,1 (pair of khalves)
    const int c0   = khp * 2 * 128 + row;       // LDS cell index
    const int wave = tid >> 6;
    const int lane = tid & 63;
    const int quad = lane >> 4;
    const int lrow = lane & 15;
    const int wr   = (wave >> 1) * 64;
    const int wc   = (wave & 1) * 64;

    f32x4 acc[4][4] = {};

    const float* ax = &x[(size_t)(m0 + row) * CC + khp * 16];
    const float* bx = &W[(size_t)(n0 + row) * CC + khp * 16];

    for (int kc = 0; kc < CC; kc += 32) {
        float a[16], b[16];
        *(float4*)&a[0]  = *(const float4*)(ax + kc + 0);
        *(float4*)&a[4]  = *(const float4*)(ax + kc + 4);
        *(float4*)&a[8]  = *(const float4*)(ax + kc + 8);
        *(float4*)&a[12] = *(const float4*)(ax + kc + 12);
        *(float4*)&b[0]  = *(const float4*)(bx + kc + 0);
        *(float4*)&b[4]  = *(const float4*)(bx + kc + 4);
        *(float4*)&b[8]  = *(const float4*)(bx + kc + 8);
        *(float4*)&b[12] = *(const float4*)(bx + kc + 12);
        __syncthreads();
        {
            f16x8 h, l;
            split8(&a[0], h, l);
            *(f16x8*)&Ah[c0 * 8] = h;         *(f16x8*)&Al[c0 * 8] = l;
            split8(&a[8], h, l);
            *(f16x8*)&Ah[(c0 + 128) * 8] = h; *(f16x8*)&Al[(c0 + 128) * 8] = l;
            split8(&b[0], h, l);
            *(f16x8*)&Bh[c0 * 8] = h;         *(f16x8*)&Bl[c0 * 8] = l;
            split8(&b[8], h, l);
            *(f16x8*)&Bh[(c0 + 128) * 8] = h; *(f16x8*)&Bl[(c0 + 128) * 8] = l;
        }
        __syncthreads();

        f16x8 ahf[4], alf[4], bhf[4], blf[4];
#pragma unroll
        for (int i = 0; i < 4; ++i) {
            int ra = quad * 128 + wr + i * 16 + lrow;
            int rb = quad * 128 + wc + i * 16 + lrow;
            ahf[i] = *(const f16x8*)&Ah[ra * 8];
            alf[i] = *(const f16x8*)&Al[ra * 8];
            bhf[i] = *(const f16x8*)&Bh[rb * 8];
            blf[i] = *(const f16x8*)&Bl[rb * 8];
        }
        if (z != 2) {
#pragma unroll
            for (int i = 0; i < 4; ++i)
#pragma unroll
                for (int j = 0; j < 4; ++j) {
                    acc[i][j] = __builtin_amdgcn_mfma_f32_16x16x32_f16(ahf[i], bhf[j], acc[i][j], 0, 0, 0);
                    acc[i][j] = __builtin_amdgcn_mfma_f32_16x16x32_f16(ahf[i], blf[j], acc[i][j], 0, 0, 0);
                    acc[i][j] = __builtin_amdgcn_mfma_f32_16x16x32_f16(alf[i], bhf[j], acc[i][j], 0, 0, 0);
                }
        } else {
#pragma unroll
            for (int i = 0; i < 4; ++i)
#pragma unroll
                for (int j = 0; j < 4; ++j)
                    acc[i][j] = __builtin_amdgcn_mfma_f32_16x16x32_f16(ahf[i], bhf[j], acc[i][j], 0, 0, 0);
        }
    }

#pragma unroll
    for (int i = 0; i < 4; ++i)
#pragma unroll
        for (int j = 0; j < 4; ++j)
#pragma unroll
            for (int r = 0; r < 4; ++r) {
                int rr = m0 + wr + i * 16 + quad * 4 + r;
                int cc = n0 + wc + j * 16 + lrow;
                float val = acc[i][j][r];
                size_t idx = (size_t)rr * HH + cc;
                if (z == 2) {
                    vv[idx] = (_Float16)val;
                } else {
                    _Float16 h = (_Float16)val;
                    _Float16 l = (_Float16)(val - (float)h);
                    if (z == 0) { qh[idx] = h; ql[idx] = l; }
                    else        { kh[idx] = h; kl[idx] = l; }
                }
            }
}

// ---------------- Kernel 2: wei_raw = (q k^T)/32, lower-tri 128-tiles --------
__global__ __launch_bounds__(256, 2) void qk_kernel(
    const _Float16* __restrict__ qh_, const _Float16* __restrict__ ql_,
    const _Float16* __restrict__ kh_, const _Float16* __restrict__ kl_,
    float* __restrict__ wei)
{
    const int st = blockIdx.x;
    const int tt = blockIdx.y;
    if (st > tt) return;
    const int b  = blockIdx.z;

    __shared__ _Float16 Ah[4096], Al[4096], Bh[4096], Bl[4096];

    const size_t base = (size_t)b * TT * HH;
    float* wb = wei + (size_t)b * TT * TT;
    const int m0 = tt * 128;
    const int n0 = st * 128;

    const int tid  = threadIdx.x;
    const int row  = tid & 127;
    const int khp  = tid >> 7;
    const int c0   = khp * 2 * 128 + row;
    const int wave = tid >> 6;
    const int lane = tid & 63;
    const int quad = lane >> 4;
    const int lrow = lane & 15;
    const int wr   = (wave >> 1) * 64;
    const int wc   = (wave & 1) * 64;

    f32x4 acc[4][4] = {};

    const _Float16* aph = &qh_[base + (size_t)(m0 + row) * HH + khp * 16];
    const _Float16* apl = &ql_[base + (size_t)(m0 + row) * HH + khp * 16];
    const _Float16* bph = &kh_[base + (size_t)(n0 + row) * HH + khp * 16];
    const _Float16* bpl = &kl_[base + (size_t)(n0 + row) * HH + khp * 16];

    for (int kc = 0; kc < HH; kc += 32) {
        f16x8 ah0 = *(const f16x8*)(aph + kc), ah1 = *(const f16x8*)(aph + kc + 8);
        f16x8 al0 = *(const f16x8*)(apl + kc), al1 = *(const f16x8*)(apl + kc + 8);
        f16x8 bh0 = *(const f16x8*)(bph + kc), bh1 = *(const f16x8*)(bph + kc + 8);
        f16x8 bl0 = *(const f16x8*)(bpl + kc), bl1 = *(const f16x8*)(bpl + kc + 8);
        __syncthreads();
        *(f16x8*)&Ah[c0 * 8] = ah0;  *(f16x8*)&Ah[(c0 + 128) * 8] = ah1;
        *(f16x8*)&Al[c0 * 8] = al0;  *(f16x8*)&Al[(c0 + 128) * 8] = al1;
        *(f16x8*)&Bh[c0 * 8] = bh0;  *(f16x8*)&Bh[(c0 + 128) * 8] = bh1;
        *(f16x8*)&Bl[c0 * 8] = bl0;  *(f16x8*)&Bl[(c0 + 128) * 8] = bl1;
        __syncthreads();

        f16x8 ahf[4], alf[4], bhf[4], blf[4];
#pragma unroll
        for (int i = 0; i < 4; ++i) {
            int ra = quad * 128 + wr + i * 16 + lrow;
            int rb = quad * 128 + wc + i * 16 + lrow;
            ahf[i] = *(const f16x8*)&Ah[ra * 8];
            alf[i] = *(const f16x8*)&Al[ra * 8];
            bhf[i] = *(const f16x8*)&Bh[rb * 8];
            blf[i] = *(const f16x8*)&Bl[rb * 8];
        }
#pragma unroll
        for (int i = 0; i < 4; ++i)
#pragma unroll
            for (int j = 0; j < 4; ++j) {
                acc[i][j] = __builtin_amdgcn_mfma_f32_16x16x32_f16(ahf[i], bhf[j], acc[i][j], 0, 0, 0);
                acc[i][j] = __builtin_amdgcn_mfma_f32_16x16x32_f16(ahf[i], blf[j], acc[i][j], 0, 0, 0);
                acc[i][j] = __builtin_amdgcn_mfma_f32_16x16x32_f16(alf[i], bhf[j], acc[i][j], 0, 0, 0);
            }
    }

    const float scale = 0.03125f;   // 1024^-0.5
#pragma unroll
    for (int i = 0; i < 4; ++i)
#pragma unroll
        for (int j = 0; j < 4; ++j)
#pragma unroll
            for (int r = 0; r < 4; ++r) {
                int rr = wr + i * 16 + quad * 4 + r;
                int cc = wc + j * 16 + lrow;
                wb[(size_t)(m0 + rr) * TT + n0 + cc] = acc[i][j][r] * scale;
            }
}

// ---------------- Kernel 3: causal row softmax in-place ----------------------
__global__ __launch_bounds__(256) void softmax_kernel(float* __restrict__ wei)
{
    const int t = blockIdx.x;
    const int b = blockIdx.y;
    float* row = wei + (size_t)b * TT * TT + (size_t)t * TT;
    const int n = t + 1;
    const int tid = threadIdx.x;

    float vals[8];
    float mx = -INFINITY;
#pragma unroll
    for (int i = 0; i < 8; ++i) {
        int s = tid + i * 256;
        vals[i] = (s < n) ? row[s] : -INFINITY;
        mx = fmaxf(mx, vals[i]);
    }
#pragma unroll
    for (int off = 32; off > 0; off >>= 1)
        mx = fmaxf(mx, __shfl_down(mx, off));

    __shared__ float redm[4];
    __shared__ float reds[4];
    if ((tid & 63) == 0) redm[tid >> 6] = mx;
    __syncthreads();
    const float m = fmaxf(fmaxf(redm[0], redm[1]), fmaxf(redm[2], redm[3]));

    float sum = 0.f;
#pragma unroll
    for (int i = 0; i < 8; ++i) {
        vals[i] = __expf(vals[i] - m);
        sum += vals[i];
    }
#pragma unroll
    for (int off = 32; off > 0; off >>= 1)
        sum += __shfl_down(sum, off);
    if ((tid & 63) == 0) reds[tid >> 6] = sum;
    __syncthreads();
    const float inv = 1.0f / (reds[0] + reds[1] + reds[2] + reds[3]);

#pragma unroll
    for (int i = 0; i < 8; ++i) {
        int s = tid + i * 256;
        row[s] = vals[i] * inv;     // masked entries: exp(-inf)*inv = 0 exactly
    }
}

// ---------------- Kernel 4: out = wei @ v (NN, 1-pass f16, causal K) ---------
__global__ __launch_bounds__(256, 2) void out_kernel(
    const float* __restrict__ wei, const _Float16* __restrict__ vv,
    float* __restrict__ out)
{
    const int nb = blockIdx.x;
    const int tt = blockIdx.y;
    const int b  = blockIdx.z;

    __shared__ _Float16 Ah[4096], Bh[4096];

    const float*    wb = wei + (size_t)b * TT * TT;
    const _Float16* vb = vv  + (size_t)b * TT * HH;
    float*          ob = out + (size_t)b * TT * HH;

    const int m0 = tt * 128;
    const int n0 = nb * 128;
    const int kend = (tt + 1) * 128;  // wei==0 above diagonal (softmax wrote 0)

    const int tid  = threadIdx.x;
    const int row  = tid & 127;       // A: t-row; B: h-col
    const int khp  = tid >> 7;
    const int c0   = khp * 2 * 128 + row;
    const int wave = tid >> 6;
    const int lane = tid & 63;
    const int quad = lane >> 4;
    const int lrow = lane & 15;
    const int wr   = (wave >> 1) * 64;
    const int wc   = (wave & 1) * 64;

    f32x4 acc[4][4] = {};

    const float* ap = &wb[(size_t)(m0 + row) * TT + khp * 16];

    for (int kc = 0; kc < kend; kc += 32) {
        float a[16];
        *(float4*)&a[0]  = *(const float4*)(ap + kc + 0);
        *(float4*)&a[4]  = *(const float4*)(ap + kc + 4);
        *(float4*)&a[8]  = *(const float4*)(ap + kc + 8);
        *(float4*)&a[12] = *(const float4*)(ap + kc + 12);
        f16x8 b0, b1;
#pragma unroll
        for (int s = 0; s < 8; ++s) {   // transpose-gather v columns
            b0[s] = vb[(size_t)(kc + khp * 16 + s) * HH + n0 + row];
            b1[s] = vb[(size_t)(kc + khp * 16 + 8 + s) * HH + n0 + row];
        }
        __syncthreads();
        {
            f16x8 h0, h1;
#pragma unroll
            for (int i = 0; i < 8; ++i) { h0[i] = (_Float16)a[i]; h1[i] = (_Float16)a[8 + i]; }
            *(f16x8*)&Ah[c0 * 8] = h0;  *(f16x8*)&Ah[(c0 + 128) * 8] = h1;
            *(f16x8*)&Bh[c0 * 8] = b0;  *(f16x8*)&Bh[(c0 + 128) * 8] = b1;
        }
        __syncthreads();

        f16x8 ahf[4], bhf[4];
#pragma unroll
        for (int i = 0; i < 4; ++i) {
            int ra = quad * 128 + wr + i * 16 + lrow;
            int rb = quad * 128 + wc + i * 16 + lrow;
            ahf[i] = *(const f16x8*)&Ah[ra * 8];
            bhf[i] = *(const f16x8*)&Bh[rb * 8];
        }
#pragma unroll
        for (int i = 0; i < 4; ++i)
#pragma unroll
            for (int j = 0; j < 4; ++j)
                acc[i][j] = __builtin_amdgcn_mfma_f32_16x16x32_f16(ahf[i], bhf[j], acc[i][j], 0, 0, 0);
    }

#pragma unroll
    for (int i = 0; i < 4; ++i)
#pragma unroll
        for (int j = 0; j < 4; ++j)
#pragma unroll
            for (int r = 0; r < 4; ++r) {
                int rr = wr + i * 16 + quad * 4 + r;
                int cc = wc + j * 16 + lrow;
                ob[(size_t)(m0 + rr) * HH + n0 + cc] = acc[i][j][r];
            }
}

extern "C" void kernel_launch(void* const* d_in, const int* in_sizes, int n_in,
                              void* d_out, int out_size, void* d_ws, size_t ws_size,
                              hipStream_t stream)
{
    const float* x  = (const float*)d_in[0];
    const float* Wk = (const float*)d_in[1];
    const float* Wq = (const float*)d_in[2];
    const float* Wv = (const float*)d_in[3];

    float* out = (float*)d_out;                 // [8,2048,1024]
    float* wei = out + (size_t)BT * HH;         // [8,2048,2048]

    _Float16* qh = (_Float16*)d_ws;             // 5 x f16[16384,1024] = 160MB
    _Float16* ql = qh + (size_t)BT * HH;
    _Float16* kh = ql + (size_t)BT * HH;
    _Float16* kl = kh + (size_t)BT * HH;
    _Float16* vv = kl + (size_t)BT * HH;

    proj_kernel<<<dim3(HH / 128, BT / 128, 3), 256, 0, stream>>>(
        x, Wq, Wk, Wv, qh, ql, kh, kl, vv);
    qk_kernel<<<dim3(TT / 128, TT / 128, BB), 256, 0, stream>>>(
        qh, ql, kh, kl, wei);
    softmax_kernel<<<dim3(TT, BB), 256, 0, stream>>>(wei);
    out_kernel<<<dim3(HH / 128, TT / 128, BB), 256, 0, stream>>>(wei, vv, out);
}

// Round 3
// 1073.014 us; speedup vs baseline: 2.4983x; 1.0725x over previous
//
#include <hip/hip_runtime.h>
#include <hip/hip_bf16.h>

// Head: causal single-head attention fwd. B=8,T=2048,C=H=1024, fp32 in.
// Outputs: out[B,T,H] fp32, wei[B,T,T] fp32 (concat in d_out).
//
// Round 3: m97-structure GEMMs. Pre-split x,W to f16 hi/lo once; all GEMM
// kernels are pure-f16 with global_load_lds(16B) staging, 128x128x32 tiles,
// 2x2 waves of 4x4 16x16x32 MFMA tiles. q/k/logits use 3-pass emulated-fp32
// (hh+hl+lh, err ~3e-3 << one-hot softmax budget); v / wei@v are 1-pass.
//
// Memory plan:
//   ws (160MB): qh ql kh kl (4x32MB f16) | vT (32MB f16 [B][H][T])
//               wei16 (67MB f16) overlays qh/ql/kh AFTER qk is done.
//   d_out wei region (134MB) doubles as split scratch: xh xl (64MB) Wh Wl
//               (12MB) -- dead before qk writes wei; softmax rewrites all.
//
// LDS: cells of 16B, index c = khalf*128 + row. global_load_lds writes
// lane-sequential cells (wave-uniform base + lane*16); fragment ds_read_b128
// hits consecutive cells -> conflict-free.
// Frag layouts (verified m89/m91): A/B[m=lane&15][k=(lane>>4)*8+j],
// C/D col=lane&15, row=(lane>>4)*4+reg.

#define BB 8
#define TT 2048
#define CC 1024
#define HH 1024
#define BT (BB * TT)

typedef _Float16 f16x8 __attribute__((ext_vector_type(8)));
typedef _Float16 f16x4 __attribute__((ext_vector_type(4)));
typedef float f32x4 __attribute__((ext_vector_type(4)));

#define AS1 __attribute__((address_space(1)))
#define AS3 __attribute__((address_space(3)))

__device__ __forceinline__ void gld16(const _Float16* g, _Float16* lds) {
    __builtin_amdgcn_global_load_lds((AS1 const unsigned int*)g,
                                     (AS3 unsigned int*)lds, 16, 0, 0);
}

// ---------------- Kernel 0: fp32 -> f16 hi/lo split --------------------------
__global__ __launch_bounds__(256) void split_kernel(
    const float* __restrict__ src, _Float16* __restrict__ dh,
    _Float16* __restrict__ dl, int n)
{
    int i = (blockIdx.x * 256 + threadIdx.x) * 4;
    if (i >= n) return;
    float4 v = *(const float4*)(src + i);
    f16x4 h, l;
    h[0] = (_Float16)v.x; l[0] = (_Float16)(v.x - (float)h[0]);
    h[1] = (_Float16)v.y; l[1] = (_Float16)(v.y - (float)h[1]);
    h[2] = (_Float16)v.z; l[2] = (_Float16)(v.z - (float)h[2]);
    h[3] = (_Float16)v.w; l[3] = (_Float16)(v.w - (float)h[3]);
    *(f16x4*)&dh[i] = h;
    *(f16x4*)&dl[i] = l;
}

// ---------------- Kernel 1: projections (NT, f16, 3-pass q/k, 1-pass v) ------
__global__ __launch_bounds__(256, 2) void proj_kernel(
    const _Float16* __restrict__ xh, const _Float16* __restrict__ xl,
    const _Float16* __restrict__ Wh, const _Float16* __restrict__ Wl, // [3][H][C]
    _Float16* __restrict__ qh, _Float16* __restrict__ ql,
    _Float16* __restrict__ kh, _Float16* __restrict__ kl,
    _Float16* __restrict__ vT)
{
    __shared__ _Float16 Ah[4096], Al[4096], Bh[4096], Bl[4096];

    const int n0 = blockIdx.x * 128;
    const int m0 = blockIdx.y * 128;
    const int z  = blockIdx.z;                 // 0:q 1:k 2:v

    const _Float16* Whz = Wh + (size_t)z * HH * CC;
    const _Float16* Wlz = Wl + (size_t)z * HH * CC;

    const int tid  = threadIdx.x;
    const int r0   = tid & 127;                // staging row
    const int k0   = tid >> 7;                 // staging k-octet (0,1)
    const int wave = tid >> 6;
    const int lane = tid & 63;
    const int quad = lane >> 4;
    const int lrow = lane & 15;
    const int wr   = (wave >> 1) * 64;
    const int wc   = (wave & 1) * 64;

    const size_t ga = (size_t)(m0 + r0) * CC + k0 * 8;   // xh/xl
    const size_t gb = (size_t)(n0 + r0) * CC + k0 * 8;   // Whz/Wlz
    const int    lds0 = tid * 8;                          // f16 idx of cell tid
    const int    lds1 = (tid + 256) * 8;

    f32x4 acc[4][4] = {};

    for (int kc = 0; kc < CC; kc += 32) {
        __syncthreads();
        gld16(xh  + ga + kc,      &Ah[lds0]);
        gld16(xh  + ga + kc + 16, &Ah[lds1]);
        gld16(Whz + gb + kc,      &Bh[lds0]);
        gld16(Whz + gb + kc + 16, &Bh[lds1]);
        if (z != 2) {
            gld16(xl  + ga + kc,      &Al[lds0]);
            gld16(xl  + ga + kc + 16, &Al[lds1]);
            gld16(Wlz + gb + kc,      &Bl[lds0]);
            gld16(Wlz + gb + kc + 16, &Bl[lds1]);
        }
        __syncthreads();

        f16x8 ahf[4], bhf[4];
#pragma unroll
        for (int i = 0; i < 4; ++i) {
            ahf[i] = *(const f16x8*)&Ah[(quad * 128 + wr + i * 16 + lrow) * 8];
            bhf[i] = *(const f16x8*)&Bh[(quad * 128 + wc + i * 16 + lrow) * 8];
        }
        if (z != 2) {
            f16x8 alf[4], blf[4];
#pragma unroll
            for (int i = 0; i < 4; ++i) {
                alf[i] = *(const f16x8*)&Al[(quad * 128 + wr + i * 16 + lrow) * 8];
                blf[i] = *(const f16x8*)&Bl[(quad * 128 + wc + i * 16 + lrow) * 8];
            }
#pragma unroll
            for (int i = 0; i < 4; ++i)
#pragma unroll
                for (int j = 0; j < 4; ++j) {
                    acc[i][j] = __builtin_amdgcn_mfma_f32_16x16x32_f16(ahf[i], bhf[j], acc[i][j], 0, 0, 0);
                    acc[i][j] = __builtin_amdgcn_mfma_f32_16x16x32_f16(ahf[i], blf[j], acc[i][j], 0, 0, 0);
                    acc[i][j] = __builtin_amdgcn_mfma_f32_16x16x32_f16(alf[i], bhf[j], acc[i][j], 0, 0, 0);
                }
        } else {
#pragma unroll
            for (int i = 0; i < 4; ++i)
#pragma unroll
                for (int j = 0; j < 4; ++j)
                    acc[i][j] = __builtin_amdgcn_mfma_f32_16x16x32_f16(ahf[i], bhf[j], acc[i][j], 0, 0, 0);
        }
    }

    if (z == 2) {
        // vT[b][h][t] scatter: 8B (4 consecutive t) per lane per (i,j)
#pragma unroll
        for (int i = 0; i < 4; ++i)
#pragma unroll
            for (int j = 0; j < 4; ++j) {
                int rrg = m0 + wr + i * 16 + quad * 4;
                int b   = rrg >> 11;
                int t0  = rrg & (TT - 1);
                int cc  = n0 + wc + j * 16 + lrow;
                f16x4 p;
#pragma unroll
                for (int r = 0; r < 4; ++r) p[r] = (_Float16)acc[i][j][r];
                *(f16x4*)&vT[(size_t)b * HH * TT + (size_t)cc * TT + t0] = p;
            }
    } else {
        _Float16* dh = (z == 0) ? qh : kh;
        _Float16* dl = (z == 0) ? ql : kl;
#pragma unroll
        for (int i = 0; i < 4; ++i)
#pragma unroll
            for (int j = 0; j < 4; ++j)
#pragma unroll
                for (int r = 0; r < 4; ++r) {
                    int rr = m0 + wr + i * 16 + quad * 4 + r;
                    int cc = n0 + wc + j * 16 + lrow;
                    float val = acc[i][j][r];
                    _Float16 h = (_Float16)val;
                    _Float16 l = (_Float16)(val - (float)h);
                    size_t idx = (size_t)rr * HH + cc;
                    dh[idx] = h; dl[idx] = l;
                }
    }
}

// ---------------- Kernel 2: wei = (q k^T)/32, lower-tri 128-tiles, 3-pass ----
__global__ __launch_bounds__(256, 2) void qk_kernel(
    const _Float16* __restrict__ qh_, const _Float16* __restrict__ ql_,
    const _Float16* __restrict__ kh_, const _Float16* __restrict__ kl_,
    float* __restrict__ wei)
{
    const int st = blockIdx.x;
    const int tt = blockIdx.y;
    if (st > tt) return;
    const int b  = blockIdx.z;

    __shared__ _Float16 Ah[4096], Al[4096], Bh[4096], Bl[4096];

    const size_t base = (size_t)b * TT * HH;
    float* wb = wei + (size_t)b * TT * TT;
    const int m0 = tt * 128;
    const int n0 = st * 128;

    const int tid  = threadIdx.x;
    const int r0   = tid & 127;
    const int k0   = tid >> 7;
    const int wave = tid >> 6;
    const int lane = tid & 63;
    const int quad = lane >> 4;
    const int lrow = lane & 15;
    const int wr   = (wave >> 1) * 64;
    const int wc   = (wave & 1) * 64;

    const size_t ga = base + (size_t)(m0 + r0) * HH + k0 * 8;
    const size_t gb = base + (size_t)(n0 + r0) * HH + k0 * 8;
    const int    lds0 = tid * 8;
    const int    lds1 = (tid + 256) * 8;

    f32x4 acc[4][4] = {};

    for (int kc = 0; kc < HH; kc += 32) {
        __syncthreads();
        gld16(qh_ + ga + kc,      &Ah[lds0]);
        gld16(qh_ + ga + kc + 16, &Ah[lds1]);
        gld16(ql_ + ga + kc,      &Al[lds0]);
        gld16(ql_ + ga + kc + 16, &Al[lds1]);
        gld16(kh_ + gb + kc,      &Bh[lds0]);
        gld16(kh_ + gb + kc + 16, &Bh[lds1]);
        gld16(kl_ + gb + kc,      &Bl[lds0]);
        gld16(kl_ + gb + kc + 16, &Bl[lds1]);
        __syncthreads();

        f16x8 ahf[4], alf[4], bhf[4], blf[4];
#pragma unroll
        for (int i = 0; i < 4; ++i) {
            ahf[i] = *(const f16x8*)&Ah[(quad * 128 + wr + i * 16 + lrow) * 8];
            alf[i] = *(const f16x8*)&Al[(quad * 128 + wr + i * 16 + lrow) * 8];
            bhf[i] = *(const f16x8*)&Bh[(quad * 128 + wc + i * 16 + lrow) * 8];
            blf[i] = *(const f16x8*)&Bl[(quad * 128 + wc + i * 16 + lrow) * 8];
        }
#pragma unroll
        for (int i = 0; i < 4; ++i)
#pragma unroll
            for (int j = 0; j < 4; ++j) {
                acc[i][j] = __builtin_amdgcn_mfma_f32_16x16x32_f16(ahf[i], bhf[j], acc[i][j], 0, 0, 0);
                acc[i][j] = __builtin_amdgcn_mfma_f32_16x16x32_f16(ahf[i], blf[j], acc[i][j], 0, 0, 0);
                acc[i][j] = __builtin_amdgcn_mfma_f32_16x16x32_f16(alf[i], bhf[j], acc[i][j], 0, 0, 0);
            }
    }

    const float scale = 0.03125f;   // 1024^-0.5
#pragma unroll
    for (int i = 0; i < 4; ++i)
#pragma unroll
        for (int j = 0; j < 4; ++j)
#pragma unroll
            for (int r = 0; r < 4; ++r) {
                int rr = wr + i * 16 + quad * 4 + r;
                int cc = wc + j * 16 + lrow;
                wb[(size_t)(m0 + rr) * TT + n0 + cc] = acc[i][j][r] * scale;
            }
}

// ---------------- Kernel 3: causal softmax; writes fp32 wei + f16 wei16 ------
__global__ __launch_bounds__(256) void softmax_kernel(
    float* __restrict__ wei, _Float16* __restrict__ wei16)
{
    const int t = blockIdx.x;
    const int b = blockIdx.y;
    float* row = wei + (size_t)b * TT * TT + (size_t)t * TT;
    _Float16* row16 = wei16 + (size_t)b * TT * TT + (size_t)t * TT;
    const int n = t + 1;
    const int tid = threadIdx.x;
    const int base = tid * 8;

    float4 v0 = *(const float4*)&row[base];
    float4 v1 = *(const float4*)&row[base + 4];
    float vals[8] = {v0.x, v0.y, v0.z, v0.w, v1.x, v1.y, v1.z, v1.w};

    float mx = -INFINITY;
#pragma unroll
    for (int i = 0; i < 8; ++i) {
        if (base + i >= n) vals[i] = -INFINITY;
        mx = fmaxf(mx, vals[i]);
    }
#pragma unroll
    for (int off = 32; off > 0; off >>= 1)
        mx = fmaxf(mx, __shfl_down(mx, off));

    __shared__ float redm[4];
    __shared__ float reds[4];
    if ((tid & 63) == 0) redm[tid >> 6] = mx;
    __syncthreads();
    const float m = fmaxf(fmaxf(redm[0], redm[1]), fmaxf(redm[2], redm[3]));

    float sum = 0.f;
#pragma unroll
    for (int i = 0; i < 8; ++i) {
        vals[i] = __expf(vals[i] - m);
        sum += vals[i];
    }
#pragma unroll
    for (int off = 32; off > 0; off >>= 1)
        sum += __shfl_down(sum, off);
    if ((tid & 63) == 0) reds[tid >> 6] = sum;
    __syncthreads();
    const float inv = 1.0f / (reds[0] + reds[1] + reds[2] + reds[3]);

    float4 o0, o1;
    f16x8 h;
#pragma unroll
    for (int i = 0; i < 8; ++i) {
        float w = vals[i] * inv;     // masked: exp(-inf)*inv = 0 exactly
        vals[i] = w;
        h[i] = (_Float16)w;
    }
    o0 = make_float4(vals[0], vals[1], vals[2], vals[3]);
    o1 = make_float4(vals[4], vals[5], vals[6], vals[7]);
    *(float4*)&row[base]     = o0;
    *(float4*)&row[base + 4] = o1;
    *(f16x8*)&row16[base]    = h;
}

// ---------------- Kernel 4: out = wei16 @ vT^T (NT, f16, causal K) -----------
__global__ __launch_bounds__(256, 2) void out_kernel(
    const _Float16* __restrict__ wei16, const _Float16* __restrict__ vT,
    float* __restrict__ out)
{
    const int nb = blockIdx.x;
    const int tt = blockIdx.y;
    const int b  = blockIdx.z;

    __shared__ _Float16 Ah[4096], Bh[4096];

    const _Float16* wb = wei16 + (size_t)b * TT * TT;
    const _Float16* vb = vT    + (size_t)b * HH * TT;
    float*          ob = out   + (size_t)b * TT * HH;

    const int m0 = tt * 128;
    const int n0 = nb * 128;
    const int kend = (tt + 1) * 128;  // wei16==0 above diagonal

    const int tid  = threadIdx.x;
    const int r0   = tid & 127;
    const int k0   = tid >> 7;
    const int wave = tid >> 6;
    const int lane = tid & 63;
    const int quad = lane >> 4;
    const int lrow = lane & 15;
    const int wr   = (wave >> 1) * 64;
    const int wc   = (wave & 1) * 64;

    const size_t ga = (size_t)(m0 + r0) * TT + k0 * 8;   // wei16 row t, k=s
    const size_t gb = (size_t)(n0 + r0) * TT + k0 * 8;   // vT row h, k=s
    const int    lds0 = tid * 8;
    const int    lds1 = (tid + 256) * 8;

    f32x4 acc[4][4] = {};

    for (int kc = 0; kc < kend; kc += 32) {
        __syncthreads();
        gld16(wb + ga + kc,      &Ah[lds0]);
        gld16(wb + ga + kc + 16, &Ah[lds1]);
        gld16(vb + gb + kc,      &Bh[lds0]);
        gld16(vb + gb + kc + 16, &Bh[lds1]);
        __syncthreads();

        f16x8 ahf[4], bhf[4];
#pragma unroll
        for (int i = 0; i < 4; ++i) {
            ahf[i] = *(const f16x8*)&Ah[(quad * 128 + wr + i * 16 + lrow) * 8];
            bhf[i] = *(const f16x8*)&Bh[(quad * 128 + wc + i * 16 + lrow) * 8];
        }
#pragma unroll
        for (int i = 0; i < 4; ++i)
#pragma unroll
            for (int j = 0; j < 4; ++j)
                acc[i][j] = __builtin_amdgcn_mfma_f32_16x16x32_f16(ahf[i], bhf[j], acc[i][j], 0, 0, 0);
    }

#pragma unroll
    for (int i = 0; i < 4; ++i)
#pragma unroll
        for (int j = 0; j < 4; ++j)
#pragma unroll
            for (int r = 0; r < 4; ++r) {
                int rr = wr + i * 16 + quad * 4 + r;
                int cc = wc + j * 16 + lrow;
                ob[(size_t)(m0 + rr) * HH + n0 + cc] = acc[i][j][r];
            }
}

extern "C" void kernel_launch(void* const* d_in, const int* in_sizes, int n_in,
                              void* d_out, int out_size, void* d_ws, size_t ws_size,
                              hipStream_t stream)
{
    const float* x  = (const float*)d_in[0];
    const float* Wk = (const float*)d_in[1];
    const float* Wq = (const float*)d_in[2];
    const float* Wv = (const float*)d_in[3];

    const size_t NX = (size_t)BT * CC;          // 16M
    const size_t NW = (size_t)HH * CC;          // 1M

    float* out = (float*)d_out;                 // [8,2048,1024] fp32
    float* wei = out + (size_t)BT * HH;         // [8,2048,2048] fp32

    // split scratch overlaid on wei region (dead before qk writes wei)
    _Float16* xh = (_Float16*)wei;              // 16M f16
    _Float16* xl = xh + NX;                     // 16M f16
    _Float16* Wh = xl + NX;                     // [3][H][C] f16
    _Float16* Wl = Wh + 3 * NW;                 //   (total overlay 76MB < 134MB)

    // ws: 160MB
    _Float16* qh = (_Float16*)d_ws;
    _Float16* ql = qh + NX;
    _Float16* kh = ql + NX;
    _Float16* kl = kh + NX;
    _Float16* vT = kl + NX;                     // [B][H][T]
    _Float16* wei16 = (_Float16*)d_ws;          // overlays qh/ql/kh after qk

    split_kernel<<<dim3(NX / 1024), 256, 0, stream>>>(x,  xh,          xl,          (int)NX);
    split_kernel<<<dim3(NW / 1024), 256, 0, stream>>>(Wq, Wh,          Wl,          (int)NW);
    split_kernel<<<dim3(NW / 1024), 256, 0, stream>>>(Wk, Wh + NW,     Wl + NW,     (int)NW);
    split_kernel<<<dim3(NW / 1024), 256, 0, stream>>>(Wv, Wh + 2 * NW, Wl + 2 * NW, (int)NW);

    proj_kernel<<<dim3(HH / 128, BT / 128, 3), 256, 0, stream>>>(
        xh, xl, Wh, Wl, qh, ql, kh, kl, vT);
    qk_kernel<<<dim3(TT / 128, TT / 128, BB), 256, 0, stream>>>(
        qh, ql, kh, kl, wei);
    softmax_kernel<<<dim3(TT, BB), 256, 0, stream>>>(wei, wei16);
    out_kernel<<<dim3(HH / 128, TT / 128, BB), 256, 0, stream>>>(wei16, vT, out);
}